// Round 1
// baseline (1333.694 us; speedup 1.0000x reference)
//
#include <hip/hip_runtime.h>

// SKA: out[n,c,y,x] = sum_{i,j} x_pad[n,c,y+i,x+j] * w[n, c%8, i*7+j, y, x]
// n=8, ic=512, h=w=96, wc=8, ks=7, pad=3. fp32 in/out.
//
// Block = 384 threads = 24 x-slots (float4 each) x 16 g-slots.
// Each thread computes 4 channels (c = (gi*16+g_slot)*8 + cw) x 4 pixels/row.
// w row (49 taps x 96 cols, 18.4 KB) staged in LDS, double-buffered with
// register prefetch one row ahead; one barrier per y-row.
//
// R1: YC 12->6 => grid 512->1024 blocks => 4 blocks/CU resident (24 waves/CU,
// 6/SIMD, LDS-capped at 151.5/160 KB) instead of 2 (12 waves/CU). Kernel was
// latency-bound (VALUBusy 18%, HBM 25%, Occ 33%): double the TLP.
// Flat grid + decode so all 16 ytiles of one (cw,n) share an XCD (b&7), making
// the 6-row x halo L2-local. launch_bounds(384,6) keeps VGPR<=85 (have 64).

typedef float f4 __attribute__((ext_vector_type(4)));

#define N_      8
#define IC_     512
#define H_      96
#define W_      96
#define WC_     8
#define KS_     7
#define NG_     4
#define GSLOTS_ 16
#define XSLOTS_ 24
#define YC_     6
#define NTHR_   (XSLOTS_ * GSLOTS_)        // 384
#define WROW_F4_ (KS_ * KS_ * XSLOTS_)     // 1176 f4 per staged w row
#define NYT_    (H_ / YC_)                 // 16 ytiles

__global__ __launch_bounds__(NTHR_, 6)
void ska_kernel(const float* __restrict__ x, const float* __restrict__ w,
                float* __restrict__ out) {
    __shared__ f4 wlds[2][WROW_F4_];       // 2 x 18816 B

    const int tid = threadIdx.x;

    // XCD-aware decode: hardware assigns consecutive blockIdx round-robin to
    // the 8 XCDs. Make (cw,n)-group a function of b&7 so all 16 ytiles of a
    // given (cw,n) (which share x halo rows) land on one XCD's L2.
    const int b     = blockIdx.x;          // 0..1023
    const int xcd   = b & 7;
    const int q     = b >> 3;              // 0..127
    const int ytile = q & (NYT_ - 1);      // 0..15
    const int cwn   = xcd + 8 * (q >> 4);  // 0..63, cwn&7 == xcd
    const int cw    = cwn & 7;
    const int n     = cwn >> 3;
    const int y0    = ytile * YC_;

    const int x_slot = tid % XSLOTS_;      // 0..23
    const int g_slot = tid / XSLOTS_;      // 0..15
    const int xq     = x_slot * 4;         // output col base

    // w as f4: index (tap*H + y)*24 + x_slot within the (n,cw) plane
    const f4* wg = reinterpret_cast<const f4*>(w)
                 + (size_t)((n * WC_ + cw) * (KS_ * KS_)) * (H_ * W_ / 4);

    // per-gi channel plane offsets (c = (gi*16 + g_slot)*8 + cw)
    int xoff[NG_], ooff[NG_];
#pragma unroll
    for (int gi = 0; gi < NG_; ++gi) {
        const int c     = (gi * GSLOTS_ + g_slot) * WC_ + cw;
        const int plane = (n * IC_ + c) * (H_ * W_);
        xoff[gi] = plane + xq - 4;   // window starts at col xq-4
        ooff[gi] = plane + xq;
    }

    f4 pre[4];

    // ---- stage w row y0 into buffer 0 ----
    {
#pragma unroll
        for (int k = 0; k < 4; ++k) {
            const int tap = g_slot + GSLOTS_ * k;          // f = tid + 384k
            if (k < 3 || g_slot == 0) {                    // tap < 49
                pre[k] = __builtin_nontemporal_load(
                    &wg[(tap * H_ + y0) * XSLOTS_ + x_slot]);
            }
        }
#pragma unroll
        for (int k = 0; k < 4; ++k) {
            const int tap = g_slot + GSLOTS_ * k;
            if (k < 3 || g_slot == 0)
                wlds[0][tap * XSLOTS_ + x_slot] = pre[k];
        }
    }
    __syncthreads();

    for (int yt = 0; yt < YC_; ++yt) {
        const int y = y0 + yt;
        const bool havenext = (yt + 1 < YC_);

        // issue next-row w prefetch early (lands during compute)
        if (havenext) {
            const int yn = y + 1;
#pragma unroll
            for (int k = 0; k < 4; ++k) {
                const int tap = g_slot + GSLOTS_ * k;
                if (k < 3 || g_slot == 0) {
                    pre[k] = __builtin_nontemporal_load(
                        &wg[(tap * H_ + yn) * XSLOTS_ + x_slot]);
                }
            }
        }

        const f4* wl = wlds[yt & 1];

        float acc[NG_][4];
#pragma unroll
        for (int gi = 0; gi < NG_; ++gi)
#pragma unroll
            for (int k = 0; k < 4; ++k) acc[gi][k] = 0.f;

#pragma unroll
        for (int i = 0; i < KS_; ++i) {
            const int ry = y + i - 3;
            if (ry >= 0 && ry < H_) {                      // block-uniform
                const int rbase = ry * W_;
                float win[NG_][12];
#pragma unroll
                for (int gi = 0; gi < NG_; ++gi) {
                    const float* rowp = x + xoff[gi] + rbase;
                    f4 A = (f4)0.f;
                    f4 C = (f4)0.f;
                    if (x_slot != 0)
                        A = *reinterpret_cast<const f4*>(rowp);
                    const f4 B = *reinterpret_cast<const f4*>(rowp + 4);
                    if (x_slot != XSLOTS_ - 1)
                        C = *reinterpret_cast<const f4*>(rowp + 8);
                    win[gi][0] = A.x;  win[gi][1] = A.y;
                    win[gi][2] = A.z;  win[gi][3] = A.w;
                    win[gi][4] = B.x;  win[gi][5] = B.y;
                    win[gi][6] = B.z;  win[gi][7] = B.w;
                    win[gi][8] = C.x;  win[gi][9] = C.y;
                    win[gi][10] = C.z; win[gi][11] = C.w;
                }
#pragma unroll
                for (int j = 0; j < KS_; ++j) {
                    const f4 w4 = wl[(i * KS_ + j) * XSLOTS_ + x_slot];
                    const float wv[4] = {w4.x, w4.y, w4.z, w4.w};
#pragma unroll
                    for (int gi = 0; gi < NG_; ++gi)
#pragma unroll
                        for (int k = 0; k < 4; ++k)
                            acc[gi][k] = __builtin_fmaf(win[gi][1 + j + k],
                                                        wv[k], acc[gi][k]);
                }
            }
        }

        // store 4 channels x f4, written exactly once -> nontemporal
#pragma unroll
        for (int gi = 0; gi < NG_; ++gi) {
            f4 o;
            o.x = acc[gi][0]; o.y = acc[gi][1];
            o.z = acc[gi][2]; o.w = acc[gi][3];
            __builtin_nontemporal_store(
                o, reinterpret_cast<f4*>(out + ooff[gi] + y * W_));
        }

        // commit prefetched w row into the other buffer; one barrier/row
        if (havenext) {
#pragma unroll
            for (int k = 0; k < 4; ++k) {
                const int tap = g_slot + GSLOTS_ * k;
                if (k < 3 || g_slot == 0)
                    wlds[(yt + 1) & 1][tap * XSLOTS_ + x_slot] = pre[k];
            }
        }
        __syncthreads();
    }
}

extern "C" void kernel_launch(void* const* d_in, const int* in_sizes, int n_in,
                              void* d_out, int out_size, void* d_ws, size_t ws_size,
                              hipStream_t stream) {
    const float* x = reinterpret_cast<const float*>(d_in[0]);
    const float* w = reinterpret_cast<const float*>(d_in[1]);
    float* out     = reinterpret_cast<float*>(d_out);

    dim3 grid(NYT_ * WC_ * N_);     // 1024 blocks, flat (XCD decode in-kernel)
    dim3 block(NTHR_);              // 384 threads
    hipLaunchKernelGGL(ska_kernel, grid, block, 0, stream, x, w, out);
}

// Round 3
// 1033.820 us; speedup vs baseline: 1.2901x; 1.2901x over previous
//
#include <hip/hip_runtime.h>

// SKA: out[n,c,y,x] = sum_{i,j} x_pad[n,c,y+i,x+j] * w[n, c%8, i*7+j, y, x]
// n=8, ic=512, h=w=96, wc=8, ks=7, pad=3. fp32 in/out.
//
// Block = 384 threads = 24 x-slots (float4 each) x 16 g-slots.
// Each thread computes 4 channels (c = (gi*16+g_slot)*8 + cw) x 4 pixels/row.
// w row (49 taps x 96 cols, 18.4 KB) staged in LDS, double-buffered with
// register prefetch one row ahead; one barrier per y-row.
//
// R1: YC 12->6 => grid 1024 blocks => 4 blocks/CU (LDS-capped, 24 waves/CU).
// R2: launch_bounds 6->4. R1's (384,6) forced VGPR 64->40 and spilled
// win/acc/pre to scratch (WRITE_SIZE 147MB->1.3GB, VALUBusy 18->4.5%).
// Natural VGPR=64 already allows 8 waves/SIMD; LDS is the real occupancy cap.
// R3: identical resubmit of R2 (container acquisition failed; kernel unrun).

typedef float f4 __attribute__((ext_vector_type(4)));

#define N_      8
#define IC_     512
#define H_      96
#define W_      96
#define WC_     8
#define KS_     7
#define NG_     4
#define GSLOTS_ 16
#define XSLOTS_ 24
#define YC_     6
#define NTHR_   (XSLOTS_ * GSLOTS_)        // 384
#define WROW_F4_ (KS_ * KS_ * XSLOTS_)     // 1176 f4 per staged w row
#define NYT_    (H_ / YC_)                 // 16 ytiles

__global__ __launch_bounds__(NTHR_, 4)
void ska_kernel(const float* __restrict__ x, const float* __restrict__ w,
                float* __restrict__ out) {
    __shared__ f4 wlds[2][WROW_F4_];       // 2 x 18816 B

    const int tid = threadIdx.x;

    // XCD-aware decode: hardware assigns consecutive blockIdx round-robin to
    // the 8 XCDs. Make (cw,n)-group a function of b&7 so all 16 ytiles of a
    // given (cw,n) (which share x halo rows) land on one XCD's L2.
    const int b     = blockIdx.x;          // 0..1023
    const int xcd   = b & 7;
    const int q     = b >> 3;              // 0..127
    const int ytile = q & (NYT_ - 1);      // 0..15
    const int cwn   = xcd + 8 * (q >> 4);  // 0..63, cwn&7 == xcd
    const int cw    = cwn & 7;
    const int n     = cwn >> 3;
    const int y0    = ytile * YC_;

    const int x_slot = tid % XSLOTS_;      // 0..23
    const int g_slot = tid / XSLOTS_;      // 0..15
    const int xq     = x_slot * 4;         // output col base

    // w as f4: index (tap*H + y)*24 + x_slot within the (n,cw) plane
    const f4* wg = reinterpret_cast<const f4*>(w)
                 + (size_t)((n * WC_ + cw) * (KS_ * KS_)) * (H_ * W_ / 4);

    // per-gi channel plane offsets (c = (gi*16 + g_slot)*8 + cw)
    int xoff[NG_], ooff[NG_];
#pragma unroll
    for (int gi = 0; gi < NG_; ++gi) {
        const int c     = (gi * GSLOTS_ + g_slot) * WC_ + cw;
        const int plane = (n * IC_ + c) * (H_ * W_);
        xoff[gi] = plane + xq - 4;   // window starts at col xq-4
        ooff[gi] = plane + xq;
    }

    f4 pre[4];

    // ---- stage w row y0 into buffer 0 ----
    {
#pragma unroll
        for (int k = 0; k < 4; ++k) {
            const int tap = g_slot + GSLOTS_ * k;          // f = tid + 384k
            if (k < 3 || g_slot == 0) {                    // tap < 49
                pre[k] = __builtin_nontemporal_load(
                    &wg[(tap * H_ + y0) * XSLOTS_ + x_slot]);
            }
        }
#pragma unroll
        for (int k = 0; k < 4; ++k) {
            const int tap = g_slot + GSLOTS_ * k;
            if (k < 3 || g_slot == 0)
                wlds[0][tap * XSLOTS_ + x_slot] = pre[k];
        }
    }
    __syncthreads();

    for (int yt = 0; yt < YC_; ++yt) {
        const int y = y0 + yt;
        const bool havenext = (yt + 1 < YC_);

        // issue next-row w prefetch early (lands during compute)
        if (havenext) {
            const int yn = y + 1;
#pragma unroll
            for (int k = 0; k < 4; ++k) {
                const int tap = g_slot + GSLOTS_ * k;
                if (k < 3 || g_slot == 0) {
                    pre[k] = __builtin_nontemporal_load(
                        &wg[(tap * H_ + yn) * XSLOTS_ + x_slot]);
                }
            }
        }

        const f4* wl = wlds[yt & 1];

        float acc[NG_][4];
#pragma unroll
        for (int gi = 0; gi < NG_; ++gi)
#pragma unroll
            for (int k = 0; k < 4; ++k) acc[gi][k] = 0.f;

#pragma unroll
        for (int i = 0; i < KS_; ++i) {
            const int ry = y + i - 3;
            if (ry >= 0 && ry < H_) {                      // block-uniform
                const int rbase = ry * W_;
                float win[NG_][12];
#pragma unroll
                for (int gi = 0; gi < NG_; ++gi) {
                    const float* rowp = x + xoff[gi] + rbase;
                    f4 A = (f4)0.f;
                    f4 C = (f4)0.f;
                    if (x_slot != 0)
                        A = *reinterpret_cast<const f4*>(rowp);
                    const f4 B = *reinterpret_cast<const f4*>(rowp + 4);
                    if (x_slot != XSLOTS_ - 1)
                        C = *reinterpret_cast<const f4*>(rowp + 8);
                    win[gi][0] = A.x;  win[gi][1] = A.y;
                    win[gi][2] = A.z;  win[gi][3] = A.w;
                    win[gi][4] = B.x;  win[gi][5] = B.y;
                    win[gi][6] = B.z;  win[gi][7] = B.w;
                    win[gi][8] = C.x;  win[gi][9] = C.y;
                    win[gi][10] = C.z; win[gi][11] = C.w;
                }
#pragma unroll
                for (int j = 0; j < KS_; ++j) {
                    const f4 w4 = wl[(i * KS_ + j) * XSLOTS_ + x_slot];
                    const float wv[4] = {w4.x, w4.y, w4.z, w4.w};
#pragma unroll
                    for (int gi = 0; gi < NG_; ++gi)
#pragma unroll
                        for (int k = 0; k < 4; ++k)
                            acc[gi][k] = __builtin_fmaf(win[gi][1 + j + k],
                                                        wv[k], acc[gi][k]);
                }
            }
        }

        // store 4 channels x f4, written exactly once -> nontemporal
#pragma unroll
        for (int gi = 0; gi < NG_; ++gi) {
            f4 o;
            o.x = acc[gi][0]; o.y = acc[gi][1];
            o.z = acc[gi][2]; o.w = acc[gi][3];
            __builtin_nontemporal_store(
                o, reinterpret_cast<f4*>(out + ooff[gi] + y * W_));
        }

        // commit prefetched w row into the other buffer; one barrier/row
        if (havenext) {
#pragma unroll
            for (int k = 0; k < 4; ++k) {
                const int tap = g_slot + GSLOTS_ * k;
                if (k < 3 || g_slot == 0)
                    wlds[(yt + 1) & 1][tap * XSLOTS_ + x_slot] = pre[k];
            }
        }
        __syncthreads();
    }
}

extern "C" void kernel_launch(void* const* d_in, const int* in_sizes, int n_in,
                              void* d_out, int out_size, void* d_ws, size_t ws_size,
                              hipStream_t stream) {
    const float* x = reinterpret_cast<const float*>(d_in[0]);
    const float* w = reinterpret_cast<const float*>(d_in[1]);
    float* out     = reinterpret_cast<float*>(d_out);

    dim3 grid(NYT_ * WC_ * N_);     // 1024 blocks, flat (XCD decode in-kernel)
    dim3 block(NTHR_);              // 384 threads
    hipLaunchKernelGGL(ska_kernel, grid, block, 0, stream, x, w, out);
}

// Round 4
// 684.882 us; speedup vs baseline: 1.9473x; 1.5095x over previous
//
#include <hip/hip_runtime.h>

// SKA: out[n,c,y,x] = sum_{i,j} x_pad[n,c,y+i,x+j] * w[n, c%8, i*7+j, y, x]
// n=8, ic=512, h=w=96, wc=8, ks=7, pad=3. fp32 in/out.
//
// Block = 768 threads = 24 x-slots (float4 each) x 32 g-slots.
// Each thread computes 2 channels (c = (gi*32+g_slot)*8 + cw) x 4 pixels/row.
// w row (49 taps x 96 cols, 18.4 KB) staged in LDS, double-buffered with
// register prefetch one row ahead; one barrier per y-row.
//
// R1: YC 12->6, 4 blocks/CU attempt. R2/R3: launch_bounds games. POST-MORTEM:
// NG=4 per-thread live set is ~90-100 VGPRs (win 48 + acc 16 + pre 16 + addr).
// Any cap <=128 spills win[] to scratch ONCE PER ROW (R3: WRITE 151->694 MB,
// FETCH +450 MB == 453 MB win spill both ways; R0's (384,3)=170-cap absorbed
// it in the unified VGPR/AGPR file). 24 waves/CU needs VGPR<=85 => NG=4 can
// NEVER reach it.
// R4: halve per-thread state instead: NG 4->2, threads 384->768, YC back to
// 12. Live set ~60-75 regs < 85. 512 blocks x 12 waves = 2 blocks/CU =
// 24 waves/CU (wave-slot cap), all co-resident. Halo factor 1.5, w read once.

typedef float f4 __attribute__((ext_vector_type(4)));

#define N_      8
#define IC_     512
#define H_      96
#define W_      96
#define WC_     8
#define KS_     7
#define NG_     2
#define GSLOTS_ 32
#define XSLOTS_ 24
#define YC_     12
#define NTHR_   (XSLOTS_ * GSLOTS_)        // 768
#define WROW_F4_ (KS_ * KS_ * XSLOTS_)     // 1176 f4 per staged w row
#define NYT_    (H_ / YC_)                 // 8 ytiles

__global__ __launch_bounds__(NTHR_, 6)
void ska_kernel(const float* __restrict__ x, const float* __restrict__ w,
                float* __restrict__ out) {
    __shared__ f4 wlds[2][WROW_F4_];       // 2 x 18816 B

    const int tid = threadIdx.x;

    // XCD-aware decode: consecutive blockIdx round-robins over 8 XCDs.
    // Group all 8 ytiles of one (cw,n) on one XCD so halo rows are L2-local.
    const int b     = blockIdx.x;          // 0..511
    const int xcd   = b & 7;
    const int q     = b >> 3;              // 0..63
    const int ytile = q & (NYT_ - 1);      // 0..7
    const int cwn   = xcd + 8 * (q >> 3);  // 0..63, cwn&7 == xcd
    const int cw    = cwn & 7;
    const int n     = cwn >> 3;
    const int y0    = ytile * YC_;

    const int x_slot = tid % XSLOTS_;      // 0..23
    const int g_slot = tid / XSLOTS_;      // 0..31
    const int xq     = x_slot * 4;         // output col base

    // w as f4: index (tap*H + y)*24 + x_slot within the (n,cw) plane
    const f4* wg = reinterpret_cast<const f4*>(w)
                 + (size_t)((n * WC_ + cw) * (KS_ * KS_)) * (H_ * W_ / 4);

    // per-gi channel plane offsets (c = (gi*32 + g_slot)*8 + cw)
    int xoff[NG_], ooff[NG_];
#pragma unroll
    for (int gi = 0; gi < NG_; ++gi) {
        const int c     = (gi * GSLOTS_ + g_slot) * WC_ + cw;
        const int plane = (n * IC_ + c) * (H_ * W_);
        xoff[gi] = plane + xq - 4;   // window starts at col xq-4
        ooff[gi] = plane + xq;
    }

    f4 pre[2];

    // ---- stage w row y0 into buffer 0 ----
    // thread covers taps {g_slot, g_slot+32}; tap<49 => k==0 or g_slot<17
    {
#pragma unroll
        for (int k = 0; k < 2; ++k) {
            const int tap = g_slot + GSLOTS_ * k;
            if (k == 0 || g_slot < KS_ * KS_ - GSLOTS_) {  // tap < 49
                pre[k] = __builtin_nontemporal_load(
                    &wg[(tap * H_ + y0) * XSLOTS_ + x_slot]);
            }
        }
#pragma unroll
        for (int k = 0; k < 2; ++k) {
            const int tap = g_slot + GSLOTS_ * k;
            if (k == 0 || g_slot < KS_ * KS_ - GSLOTS_)
                wlds[0][tap * XSLOTS_ + x_slot] = pre[k];
        }
    }
    __syncthreads();

    for (int yt = 0; yt < YC_; ++yt) {
        const int y = y0 + yt;
        const bool havenext = (yt + 1 < YC_);

        // issue next-row w prefetch early (lands during compute)
        if (havenext) {
            const int yn = y + 1;
#pragma unroll
            for (int k = 0; k < 2; ++k) {
                const int tap = g_slot + GSLOTS_ * k;
                if (k == 0 || g_slot < KS_ * KS_ - GSLOTS_) {
                    pre[k] = __builtin_nontemporal_load(
                        &wg[(tap * H_ + yn) * XSLOTS_ + x_slot]);
                }
            }
        }

        const f4* wl = wlds[yt & 1];

        float acc[NG_][4];
#pragma unroll
        for (int gi = 0; gi < NG_; ++gi)
#pragma unroll
            for (int k = 0; k < 4; ++k) acc[gi][k] = 0.f;

#pragma unroll
        for (int i = 0; i < KS_; ++i) {
            const int ry = y + i - 3;
            if (ry >= 0 && ry < H_) {                      // block-uniform
                const int rbase = ry * W_;
                float win[NG_][12];
#pragma unroll
                for (int gi = 0; gi < NG_; ++gi) {
                    const float* rowp = x + xoff[gi] + rbase;
                    f4 A = (f4)0.f;
                    f4 C = (f4)0.f;
                    if (x_slot != 0)
                        A = *reinterpret_cast<const f4*>(rowp);
                    const f4 B = *reinterpret_cast<const f4*>(rowp + 4);
                    if (x_slot != XSLOTS_ - 1)
                        C = *reinterpret_cast<const f4*>(rowp + 8);
                    win[gi][0] = A.x;  win[gi][1] = A.y;
                    win[gi][2] = A.z;  win[gi][3] = A.w;
                    win[gi][4] = B.x;  win[gi][5] = B.y;
                    win[gi][6] = B.z;  win[gi][7] = B.w;
                    win[gi][8] = C.x;  win[gi][9] = C.y;
                    win[gi][10] = C.z; win[gi][11] = C.w;
                }
#pragma unroll
                for (int j = 0; j < KS_; ++j) {
                    const f4 w4 = wl[(i * KS_ + j) * XSLOTS_ + x_slot];
                    const float wv[4] = {w4.x, w4.y, w4.z, w4.w};
#pragma unroll
                    for (int gi = 0; gi < NG_; ++gi)
#pragma unroll
                        for (int k = 0; k < 4; ++k)
                            acc[gi][k] = __builtin_fmaf(win[gi][1 + j + k],
                                                        wv[k], acc[gi][k]);
                }
            }
        }

        // store 2 channels x f4, written exactly once -> nontemporal
#pragma unroll
        for (int gi = 0; gi < NG_; ++gi) {
            f4 o;
            o.x = acc[gi][0]; o.y = acc[gi][1];
            o.z = acc[gi][2]; o.w = acc[gi][3];
            __builtin_nontemporal_store(
                o, reinterpret_cast<f4*>(out + ooff[gi] + y * W_));
        }

        // commit prefetched w row into the other buffer; one barrier/row
        if (havenext) {
#pragma unroll
            for (int k = 0; k < 2; ++k) {
                const int tap = g_slot + GSLOTS_ * k;
                if (k == 0 || g_slot < KS_ * KS_ - GSLOTS_)
                    wlds[(yt + 1) & 1][tap * XSLOTS_ + x_slot] = pre[k];
            }
        }
        __syncthreads();
    }
}

extern "C" void kernel_launch(void* const* d_in, const int* in_sizes, int n_in,
                              void* d_out, int out_size, void* d_ws, size_t ws_size,
                              hipStream_t stream) {
    const float* x = reinterpret_cast<const float*>(d_in[0]);
    const float* w = reinterpret_cast<const float*>(d_in[1]);
    float* out     = reinterpret_cast<float*>(d_out);

    dim3 grid(NYT_ * WC_ * N_);     // 512 blocks, flat (XCD decode in-kernel)
    dim3 block(NTHR_);              // 768 threads = 12 waves
    hipLaunchKernelGGL(ska_kernel, grid, block, 0, stream, x, w, out);
}

// Round 5
// 532.548 us; speedup vs baseline: 2.5044x; 1.2860x over previous
//
#include <hip/hip_runtime.h>

// SKA: out[n,c,y,x] = sum_{i,j} x_pad[n,c,y+i,x+j] * w[n, c%8, i*7+j, y, x]
// n=8, ic=512, h=w=96, wc=8, ks=7, pad=3. fp32 in/out.
//
// Block = 384 threads = 24 x-slots (float4 each) x 16 g-slots, NG=2 channels
// per thread, 12 y-rows per block; grid g-halved: 1024 blocks cover
// (8 ytile) x (2 gh) x (8 cw) x (8 n). w row (49 taps x 96 cols, 18.4 KB)
// staged in LDS via global_load_lds DMA, double-buffered, 1 barrier/row.
//
// SESSION LEDGER:
// R1/R3/R4: any launch-bounds cap <=128 spilled the x-window to scratch
//   (R4: WRITE 612MB = +461MB == win[2][12] per row exactly). Root cause:
//   full unroll of the 7-tap i-loop hoists ~7 rows of A/B/C loads; true
//   demand ~130-170 regs (R0's (384,3)=170 budget absorbed it in AGPRs).
// R5: kill the demand, not the cap:
//   (a) #pragma unroll 1 on i-loop -> no cross-row load hoisting (~60 regs)
//   (b) w staged by __builtin_amdgcn_global_load_lds (dst = wave-uniform
//       base + lane*16 == our tid+384k layout) -> pre[] regs + staging VALU
//       gone; aux=0 keeps w cached so the gh-twin block L2-hits it.
//   (c) 384-thr blocks: 4 blocks/CU (LDS 155.6/160 KB) = 24 waves/CU,
//       graceful 3-block fallback if VGPR in 86..128.

typedef float f4 __attribute__((ext_vector_type(4)));
typedef const __attribute__((address_space(1))) f4 gf4;
typedef __attribute__((address_space(3))) f4 lf4;

#define N_      8
#define IC_     512
#define H_      96
#define W_      96
#define WC_     8
#define KS_     7
#define NG_     2
#define GSLOTS_ 16
#define XSLOTS_ 24
#define YC_     12
#define NTHR_   (XSLOTS_ * GSLOTS_)        // 384
#define WROW_F4_ (KS_ * KS_ * XSLOTS_)     // 1176 f4 per staged w row
#define WBUF_F4_ (WROW_F4_ + 40)           // pad: stray lane-writes of the
                                           // masked DMA round land in pad
#define NYT_    (H_ / YC_)                 // 8 ytiles

__global__ __launch_bounds__(NTHR_, 4)
void ska_kernel(const float* __restrict__ x, const float* __restrict__ w,
                float* __restrict__ out) {
    __shared__ f4 wlds[2][WBUF_F4_];       // 2 x 19456 B = 38912 B

    const int tid = threadIdx.x;

    // XCD-aware decode: consecutive blockIdx round-robins over 8 XCDs.
    // Keep all ytiles + both gh halves of one (cw,n) on one XCD (L2-local
    // halo rows and shared w plane).
    const int b     = blockIdx.x;          // 0..1023
    const int xcd   = b & 7;
    const int q     = b >> 3;              // 0..127
    const int ytile = q & (NYT_ - 1);      // 0..7
    const int gh    = (q >> 3) & 1;        // 0..1  (g-half)
    const int cwn   = xcd + 8 * (q >> 4);  // 0..63, cwn&7 == xcd
    const int cw    = cwn & 7;
    const int n     = cwn >> 3;
    const int y0    = ytile * YC_;

    const int x_slot = tid % XSLOTS_;      // 0..23
    const int g_slot = tid / XSLOTS_;      // 0..15
    const int xq     = x_slot * 4;         // output col base
    const int wavebase = tid & ~63;        // wave-uniform f4 base for DMA

    // w as f4: index (tap*H + y)*24 + x_slot within the (n,cw) plane
    const f4* wg = reinterpret_cast<const f4*>(w)
                 + (size_t)((n * WC_ + cw) * (KS_ * KS_)) * (H_ * W_ / 4);

    // per-gi channel plane offsets: g = gh*32 + gi*16 + g_slot, c = g*8 + cw
    int xoff[NG_], ooff[NG_];
#pragma unroll
    for (int gi = 0; gi < NG_; ++gi) {
        const int g     = gh * (NG_ * GSLOTS_) + gi * GSLOTS_ + g_slot;
        const int c     = g * WC_ + cw;
        const int plane = (n * IC_ + c) * (H_ * W_);
        xoff[gi] = plane + xq - 4;   // window starts at col xq-4
        ooff[gi] = plane + xq;
    }

    // stage one w row into wlds[nb] via direct global->LDS DMA.
    // f4 slot tid+384k == wave-uniform (wavebase+384k) + lane  -> legal DMA.
    auto stage = [&](int nb, int yrow) {
#pragma unroll
        for (int k = 0; k < 4; ++k) {
            const int tap = g_slot + GSLOTS_ * k;
            if (k < 3 || g_slot == 0) {                    // tap < 49
                __builtin_amdgcn_global_load_lds(
                    (gf4*)(wg + (tap * H_ + yrow) * XSLOTS_ + x_slot),
                    (lf4*)(&wlds[nb][wavebase + 384 * k]),
                    16, 0, 0);
            }
        }
    };

    stage(0, y0);
    __syncthreads();   // compiler drains vmcnt(0) before s_barrier

    for (int yt = 0; yt < YC_; ++yt) {
        const int y = y0 + yt;

        // issue next-row w DMA immediately; lands during compute, drained by
        // the end-of-row barrier.
        if (yt + 1 < YC_) stage((yt + 1) & 1, y + 1);

        const f4* wl = &wlds[yt & 1][0];

        float acc[NG_][4];
#pragma unroll
        for (int gi = 0; gi < NG_; ++gi)
#pragma unroll
            for (int k = 0; k < 4; ++k) acc[gi][k] = 0.f;

#pragma unroll 1   // CRITICAL: full unroll hoists 7 rows of A/B/C -> spills
        for (int i = 0; i < KS_; ++i) {
            const int ry = y + i - 3;
            if (ry >= 0 && ry < H_) {                      // block-uniform
                const int rbase = ry * W_;
                float win[NG_][12];
#pragma unroll
                for (int gi = 0; gi < NG_; ++gi) {
                    const float* rowp = x + xoff[gi] + rbase;
                    f4 A = (f4)0.f;
                    f4 C = (f4)0.f;
                    if (x_slot != 0)
                        A = *reinterpret_cast<const f4*>(rowp);
                    const f4 B = *reinterpret_cast<const f4*>(rowp + 4);
                    if (x_slot != XSLOTS_ - 1)
                        C = *reinterpret_cast<const f4*>(rowp + 8);
                    win[gi][0] = A.x;  win[gi][1] = A.y;
                    win[gi][2] = A.z;  win[gi][3] = A.w;
                    win[gi][4] = B.x;  win[gi][5] = B.y;
                    win[gi][6] = B.z;  win[gi][7] = B.w;
                    win[gi][8] = C.x;  win[gi][9] = C.y;
                    win[gi][10] = C.z; win[gi][11] = C.w;
                }
                const f4* wrow = wl + (i * KS_) * XSLOTS_ + x_slot;
#pragma unroll
                for (int j = 0; j < KS_; ++j) {
                    const f4 w4 = wrow[j * XSLOTS_];
                    const float wv[4] = {w4.x, w4.y, w4.z, w4.w};
#pragma unroll
                    for (int gi = 0; gi < NG_; ++gi)
#pragma unroll
                        for (int k = 0; k < 4; ++k)
                            acc[gi][k] = __builtin_fmaf(win[gi][1 + j + k],
                                                        wv[k], acc[gi][k]);
                }
            }
        }

        // store 2 channels x f4, written exactly once -> nontemporal
#pragma unroll
        for (int gi = 0; gi < NG_; ++gi) {
            f4 o;
            o.x = acc[gi][0]; o.y = acc[gi][1];
            o.z = acc[gi][2]; o.w = acc[gi][3];
            __builtin_nontemporal_store(
                o, reinterpret_cast<f4*>(out + ooff[gi] + y * W_));
        }

        // one barrier/row: drains the w DMA (vmcnt) and fences buffer reuse
        __syncthreads();
    }
}

extern "C" void kernel_launch(void* const* d_in, const int* in_sizes, int n_in,
                              void* d_out, int out_size, void* d_ws, size_t ws_size,
                              hipStream_t stream) {
    const float* x = reinterpret_cast<const float*>(d_in[0]);
    const float* w = reinterpret_cast<const float*>(d_in[1]);
    float* out     = reinterpret_cast<float*>(d_out);

    dim3 grid(NYT_ * 2 * WC_ * N_);  // 1024 blocks, flat (XCD decode in-kernel)
    dim3 block(NTHR_);               // 384 threads = 6 waves
    hipLaunchKernelGGL(ska_kernel, grid, block, 0, stream, x, w, out);
}

// Round 6
// 532.106 us; speedup vs baseline: 2.5064x; 1.0008x over previous
//
#include <hip/hip_runtime.h>

// SKA: out[n,c,y,x] = sum_{i,j} x_pad[n,c,y+i,x+j] * w[n, c%8, i*7+j, y, x]
// n=8, ic=512, h=w=96, wc=8, ks=7, pad=3. fp32 in/out.
//
// Block = 384 threads = 24 x-slots (float4 each) x 16 g-slots, NG=2 channels
// per thread, 12 y-rows per block; grid g-halved: 1024 blocks cover
// (8 ytile) x (2 gh) x (8 cw) x (8 n). w row (49 taps x 96 cols, 18.4 KB)
// staged in LDS via global_load_lds DMA, double-buffered, 1 barrier/row.
//
// SESSION LEDGER:
// R1/R3/R4: launch-bounds caps <=128 + FULL i-unroll spilled the hoisted
//   x-window to scratch (R4: WRITE 612MB == win[2][12]/row exactly).
// R5: #pragma unroll 1 + global_load_lds staging killed the demand: spill
//   GONE (WRITE 147MB), dur 482->332us. But occupancy stuck at 35.7% =
//   12 waves/CU: launch_bounds(384,4) => budget 128 regs => 4 waves/SIMD =>
//   16 slots/CU; 6-wave blocks => floor(16/6)=2 blocks. Budget, not demand
//   (arch VGPR=40), was the cap.
// R6: bounds (384,6) => budget 85 => 6 waves/SIMD => 24 slots => 4 blocks/CU
//   (LDS 155.6/160 KB exact fit). Same bounds as R1's disaster, but the lean
//   R5 structure (~40-70 live regs) fits 85 without scratch.

typedef float f4 __attribute__((ext_vector_type(4)));
typedef const __attribute__((address_space(1))) f4 gf4;
typedef __attribute__((address_space(3))) f4 lf4;

#define N_      8
#define IC_     512
#define H_      96
#define W_      96
#define WC_     8
#define KS_     7
#define NG_     2
#define GSLOTS_ 16
#define XSLOTS_ 24
#define YC_     12
#define NTHR_   (XSLOTS_ * GSLOTS_)        // 384
#define WROW_F4_ (KS_ * KS_ * XSLOTS_)     // 1176 f4 per staged w row
#define WBUF_F4_ (WROW_F4_ + 40)           // pad: stray lane-writes of the
                                           // masked DMA round land in pad
#define NYT_    (H_ / YC_)                 // 8 ytiles

__global__ __launch_bounds__(NTHR_, 6)
void ska_kernel(const float* __restrict__ x, const float* __restrict__ w,
                float* __restrict__ out) {
    __shared__ f4 wlds[2][WBUF_F4_];       // 2 x 19456 B = 38912 B

    const int tid = threadIdx.x;

    // XCD-aware decode: consecutive blockIdx round-robins over 8 XCDs.
    // Keep all ytiles + both gh halves of one (cw,n) on one XCD (L2-local
    // halo rows and shared w plane).
    const int b     = blockIdx.x;          // 0..1023
    const int xcd   = b & 7;
    const int q     = b >> 3;              // 0..127
    const int ytile = q & (NYT_ - 1);      // 0..7
    const int gh    = (q >> 3) & 1;        // 0..1  (g-half)
    const int cwn   = xcd + 8 * (q >> 4);  // 0..63, cwn&7 == xcd
    const int cw    = cwn & 7;
    const int n     = cwn >> 3;
    const int y0    = ytile * YC_;

    const int x_slot = tid % XSLOTS_;      // 0..23
    const int g_slot = tid / XSLOTS_;      // 0..15
    const int xq     = x_slot * 4;         // output col base
    const int wavebase = tid & ~63;        // wave-uniform f4 base for DMA

    // w as f4: index (tap*H + y)*24 + x_slot within the (n,cw) plane
    const f4* wg = reinterpret_cast<const f4*>(w)
                 + (size_t)((n * WC_ + cw) * (KS_ * KS_)) * (H_ * W_ / 4);

    // per-gi channel plane offsets: g = gh*32 + gi*16 + g_slot, c = g*8 + cw
    int xoff[NG_], ooff[NG_];
#pragma unroll
    for (int gi = 0; gi < NG_; ++gi) {
        const int g     = gh * (NG_ * GSLOTS_) + gi * GSLOTS_ + g_slot;
        const int c     = g * WC_ + cw;
        const int plane = (n * IC_ + c) * (H_ * W_);
        xoff[gi] = plane + xq - 4;   // window starts at col xq-4
        ooff[gi] = plane + xq;
    }

    // stage one w row into wlds[nb] via direct global->LDS DMA.
    // f4 slot tid+384k == wave-uniform (wavebase+384k) + lane  -> legal DMA.
    auto stage = [&](int nb, int yrow) {
#pragma unroll
        for (int k = 0; k < 4; ++k) {
            const int tap = g_slot + GSLOTS_ * k;
            if (k < 3 || g_slot == 0) {                    // tap < 49
                __builtin_amdgcn_global_load_lds(
                    (gf4*)(wg + (tap * H_ + yrow) * XSLOTS_ + x_slot),
                    (lf4*)(&wlds[nb][wavebase + 384 * k]),
                    16, 0, 0);
            }
        }
    };

    stage(0, y0);
    __syncthreads();   // compiler drains vmcnt(0) before s_barrier

    for (int yt = 0; yt < YC_; ++yt) {
        const int y = y0 + yt;

        // issue next-row w DMA immediately; lands during compute, drained by
        // the end-of-row barrier.
        if (yt + 1 < YC_) stage((yt + 1) & 1, y + 1);

        const f4* wl = &wlds[yt & 1][0];

        float acc[NG_][4];
#pragma unroll
        for (int gi = 0; gi < NG_; ++gi)
#pragma unroll
            for (int k = 0; k < 4; ++k) acc[gi][k] = 0.f;

#pragma unroll 1   // CRITICAL: full unroll hoists 7 rows of A/B/C -> spills
        for (int i = 0; i < KS_; ++i) {
            const int ry = y + i - 3;
            if (ry >= 0 && ry < H_) {                      // block-uniform
                const int rbase = ry * W_;
                float win[NG_][12];
#pragma unroll
                for (int gi = 0; gi < NG_; ++gi) {
                    const float* rowp = x + xoff[gi] + rbase;
                    f4 A = (f4)0.f;
                    f4 C = (f4)0.f;
                    if (x_slot != 0)
                        A = *reinterpret_cast<const f4*>(rowp);
                    const f4 B = *reinterpret_cast<const f4*>(rowp + 4);
                    if (x_slot != XSLOTS_ - 1)
                        C = *reinterpret_cast<const f4*>(rowp + 8);
                    win[gi][0] = A.x;  win[gi][1] = A.y;
                    win[gi][2] = A.z;  win[gi][3] = A.w;
                    win[gi][4] = B.x;  win[gi][5] = B.y;
                    win[gi][6] = B.z;  win[gi][7] = B.w;
                    win[gi][8] = C.x;  win[gi][9] = C.y;
                    win[gi][10] = C.z; win[gi][11] = C.w;
                }
                const f4* wrow = wl + (i * KS_) * XSLOTS_ + x_slot;
#pragma unroll
                for (int j = 0; j < KS_; ++j) {
                    const f4 w4 = wrow[j * XSLOTS_];
                    const float wv[4] = {w4.x, w4.y, w4.z, w4.w};
#pragma unroll
                    for (int gi = 0; gi < NG_; ++gi)
#pragma unroll
                        for (int k = 0; k < 4; ++k)
                            acc[gi][k] = __builtin_fmaf(win[gi][1 + j + k],
                                                        wv[k], acc[gi][k]);
                }
            }
        }

        // store 2 channels x f4, written exactly once -> nontemporal
#pragma unroll
        for (int gi = 0; gi < NG_; ++gi) {
            f4 o;
            o.x = acc[gi][0]; o.y = acc[gi][1];
            o.z = acc[gi][2]; o.w = acc[gi][3];
            __builtin_nontemporal_store(
                o, reinterpret_cast<f4*>(out + ooff[gi] + y * W_));
        }

        // one barrier/row: drains the w DMA (vmcnt) and fences buffer reuse
        __syncthreads();
    }
}

extern "C" void kernel_launch(void* const* d_in, const int* in_sizes, int n_in,
                              void* d_out, int out_size, void* d_ws, size_t ws_size,
                              hipStream_t stream) {
    const float* x = reinterpret_cast<const float*>(d_in[0]);
    const float* w = reinterpret_cast<const float*>(d_in[1]);
    float* out     = reinterpret_cast<float*>(d_out);

    dim3 grid(NYT_ * 2 * WC_ * N_);  // 1024 blocks, flat (XCD decode in-kernel)
    dim3 block(NTHR_);               // 384 threads = 6 waves
    hipLaunchKernelGGL(ska_kernel, grid, block, 0, stream, x, w, out);
}

// Round 7
// 513.916 us; speedup vs baseline: 2.5952x; 1.0354x over previous
//
#include <hip/hip_runtime.h>

// SKA: out[n,c,y,x] = sum_{i,j} x_pad[n,c,y+i,x+j] * w[n, c%8, i*7+j, y, x]
// n=8, ic=512, h=w=96, wc=8, ks=7, pad=3. fp32 in/out.
//
// Block = 384 threads = 24 x-slots (float4 each) x 16 g-slots, NG=2 channels
// per thread, 12 y-rows per block; grid g-halved: 1024 blocks cover
// (8 ytile) x (2 gh) x (8 cw) x (8 n).
//
// SESSION LEDGER:
// R1-R4: full i-unroll hoisted 7 tap-rows of x-window -> demand ~170 regs ->
//   any bounds cap <=128 spilled win[] per row (R4 WRITE 612MB).
// R5: unroll 1 + global_load_lds w staging: spill gone (WRITE 147MB),
//   482->332us. Occupancy stuck 35.7% = 2 blocks/CU.
// R6: bounds (384,6): ZERO delta -> launch_bounds 2nd arg does NOT set
//   residency; resources do. VGPR 40, slots, threads all allow 4 blocks;
//   only LDS can be the cap -> hypothesis: SPI rounds LDS alloc to pow2
//   (38912 -> 64KB -> floor(160/64) = 2 blocks, matching ALL rounds).
// R7: single w-row buffer (19456B -> 32KB granule -> LDS allows 5 blocks;
//   grid gives 4/CU = 24 waves). Prefetch overlap kept via registers:
//   issue next-row w->pre[4] before compute; barrier; pre->LDS; barrier.

typedef float f4 __attribute__((ext_vector_type(4)));
typedef const __attribute__((address_space(1))) f4 gf4;
typedef __attribute__((address_space(3))) f4 lf4;

#define N_      8
#define IC_     512
#define H_      96
#define W_      96
#define WC_     8
#define KS_     7
#define NG_     2
#define GSLOTS_ 16
#define XSLOTS_ 24
#define YC_     12
#define NTHR_   (XSLOTS_ * GSLOTS_)        // 384
#define WROW_F4_ (KS_ * KS_ * XSLOTS_)     // 1176 f4 per staged w row
#define WBUF_F4_ (WROW_F4_ + 40)           // pad: masked-DMA stray slots
#define NYT_    (H_ / YC_)                 // 8 ytiles

__global__ __launch_bounds__(NTHR_, 4)
void ska_kernel(const float* __restrict__ x, const float* __restrict__ w,
                float* __restrict__ out) {
    __shared__ f4 wlds[WBUF_F4_];          // 19456 B single buffer

    const int tid = threadIdx.x;

    // XCD-aware decode: consecutive blockIdx round-robins over 8 XCDs.
    // Keep all ytiles + both gh halves of one (cw,n) on one XCD (L2-local
    // halo rows and shared w plane).
    const int b     = blockIdx.x;          // 0..1023
    const int xcd   = b & 7;
    const int q     = b >> 3;              // 0..127
    const int ytile = q & (NYT_ - 1);      // 0..7
    const int gh    = (q >> 3) & 1;        // 0..1  (g-half)
    const int cwn   = xcd + 8 * (q >> 4);  // 0..63, cwn&7 == xcd
    const int cw    = cwn & 7;
    const int n     = cwn >> 3;
    const int y0    = ytile * YC_;

    const int x_slot = tid % XSLOTS_;      // 0..23
    const int g_slot = tid / XSLOTS_;      // 0..15
    const int xq     = x_slot * 4;         // output col base
    const int wavebase = tid & ~63;        // wave-uniform f4 base for DMA

    // w as f4: index (tap*H + y)*24 + x_slot within the (n,cw) plane
    const f4* wg = reinterpret_cast<const f4*>(w)
                 + (size_t)((n * WC_ + cw) * (KS_ * KS_)) * (H_ * W_ / 4);

    // per-gi channel plane offsets: g = gh*32 + gi*16 + g_slot, c = g*8 + cw
    int xoff[NG_], ooff[NG_];
#pragma unroll
    for (int gi = 0; gi < NG_; ++gi) {
        const int g     = gh * (NG_ * GSLOTS_) + gi * GSLOTS_ + g_slot;
        const int c     = g * WC_ + cw;
        const int plane = (n * IC_ + c) * (H_ * W_);
        xoff[gi] = plane + xq - 4;   // window starts at col xq-4
        ooff[gi] = plane + xq;
    }

    // ---- initial stage of row y0 via global->LDS DMA ----
    // f4 slot tid+384k == wave-uniform (wavebase+384k) + lane -> legal DMA.
    {
#pragma unroll
        for (int k = 0; k < 4; ++k) {
            const int tap = g_slot + GSLOTS_ * k;
            if (k < 3 || g_slot == 0) {                    // tap < 49
                __builtin_amdgcn_global_load_lds(
                    (gf4*)(wg + (tap * H_ + y0) * XSLOTS_ + x_slot),
                    (lf4*)(&wlds[wavebase + 384 * k]),
                    16, 0, 0);
            }
        }
    }
    __syncthreads();   // compiler drains vmcnt(0) before s_barrier

    f4 pre[4];

    for (int yt = 0; yt < YC_; ++yt) {
        const int y = y0 + yt;
        const bool havenext = (yt + 1 < YC_);   // block-uniform

        // issue next-row w prefetch (global->reg) now; the s_waitcnt for it
        // sits at the pre->LDS commit, so the loads overlap all of compute.
        // Plain (cacheable) loads: the gh-twin block reuses this row via L2.
        if (havenext) {
            const int yn = y + 1;
#pragma unroll
            for (int k = 0; k < 4; ++k) {
                const int tap = g_slot + GSLOTS_ * k;
                if (k < 3 || g_slot == 0)
                    pre[k] = wg[(tap * H_ + yn) * XSLOTS_ + x_slot];
            }
        }

        float acc[NG_][4];
#pragma unroll
        for (int gi = 0; gi < NG_; ++gi)
#pragma unroll
            for (int k = 0; k < 4; ++k) acc[gi][k] = 0.f;

#pragma unroll 1   // CRITICAL: full unroll hoists 7 rows of A/B/C -> spills
        for (int i = 0; i < KS_; ++i) {
            const int ry = y + i - 3;
            if (ry >= 0 && ry < H_) {                      // block-uniform
                const int rbase = ry * W_;
                float win[NG_][12];
#pragma unroll
                for (int gi = 0; gi < NG_; ++gi) {
                    const float* rowp = x + xoff[gi] + rbase;
                    f4 A = (f4)0.f;
                    f4 C = (f4)0.f;
                    if (x_slot != 0)
                        A = *reinterpret_cast<const f4*>(rowp);
                    const f4 B = *reinterpret_cast<const f4*>(rowp + 4);
                    if (x_slot != XSLOTS_ - 1)
                        C = *reinterpret_cast<const f4*>(rowp + 8);
                    win[gi][0] = A.x;  win[gi][1] = A.y;
                    win[gi][2] = A.z;  win[gi][3] = A.w;
                    win[gi][4] = B.x;  win[gi][5] = B.y;
                    win[gi][6] = B.z;  win[gi][7] = B.w;
                    win[gi][8] = C.x;  win[gi][9] = C.y;
                    win[gi][10] = C.z; win[gi][11] = C.w;
                }
                const f4* wrow = reinterpret_cast<const f4*>(&wlds[0])
                               + (i * KS_) * XSLOTS_ + x_slot;
#pragma unroll
                for (int j = 0; j < KS_; ++j) {
                    const f4 w4 = wrow[j * XSLOTS_];
                    const float wv[4] = {w4.x, w4.y, w4.z, w4.w};
#pragma unroll
                    for (int gi = 0; gi < NG_; ++gi)
#pragma unroll
                        for (int k = 0; k < 4; ++k)
                            acc[gi][k] = __builtin_fmaf(win[gi][1 + j + k],
                                                        wv[k], acc[gi][k]);
                }
            }
        }

        // store 2 channels x f4, written exactly once -> nontemporal
#pragma unroll
        for (int gi = 0; gi < NG_; ++gi) {
            f4 o;
            o.x = acc[gi][0]; o.y = acc[gi][1];
            o.z = acc[gi][2]; o.w = acc[gi][3];
            __builtin_nontemporal_store(
                o, reinterpret_cast<f4*>(out + ooff[gi] + y * W_));
        }

        // single-buffer row swap: drain readers, commit pre->LDS, publish.
        if (havenext) {                      // uniform -> barriers legal
            __syncthreads();                 // all reads of row y done
#pragma unroll
            for (int k = 0; k < 4; ++k) {
                const int tap = g_slot + GSLOTS_ * k;
                if (k < 3 || g_slot == 0)
                    wlds[tid + 384 * k] = pre[k];   // slot == tap*24+x_slot
            }
            __syncthreads();                 // row y+1 visible
        }
    }
}

extern "C" void kernel_launch(void* const* d_in, const int* in_sizes, int n_in,
                              void* d_out, int out_size, void* d_ws, size_t ws_size,
                              hipStream_t stream) {
    const float* x = reinterpret_cast<const float*>(d_in[0]);
    const float* w = reinterpret_cast<const float*>(d_in[1]);
    float* out     = reinterpret_cast<float*>(d_out);

    dim3 grid(NYT_ * 2 * WC_ * N_);  // 1024 blocks, flat (XCD decode in-kernel)
    dim3 block(NTHR_);               // 384 threads = 6 waves
    hipLaunchKernelGGL(ska_kernel, grid, block, 0, stream, x, w, out);
}

// Round 8
// 435.552 us; speedup vs baseline: 3.0621x; 1.1799x over previous
//
#include <hip/hip_runtime.h>

// SKA: out[n,c,y,x] = sum_{i,j} x_pad[n,c,y+i,x+j] * w[n, c%8, i*7+j, y, x]
// n=8, ic=512, h=w=96, wc=8, ks=7, pad=3. fp32 in/out.
//
// Block = 768 threads = 24 x-slots (float4 each) x 32 g-slots, NG=2 channels
// per thread, 12 y-rows; 512 blocks cover (8 ytile) x (8 cw) x (8 n).
// w row (49 taps x 96 cols, 18.4 KB) staged via global_load_lds DMA,
// double-buffered, one barrier per y-row.
//
// SESSION LEDGER:
// R1-R4: full i-unroll hoists 7 tap-rows of x-window -> ~170-reg demand ->
//   spills under any cap <=128 (R4 WRITE 612MB == win[2][12]/row).
// R5: unroll 1 + global_load_lds staging: spill gone, 482->332us, but occ
//   35.7% (2 blocks/CU). R6: bounds 4->6 zero delta (bounds don't set
//   residency). R7: LDS 38.9K->19.5K zero occupancy delta (not LDS either).
//   EVERY 384-thr config = 2 blocks/CU; only 768-thr (R4) ever reached
//   24 waves/CU (69.8%). Block size is the only knob that moved residency.
// R8: 768-thr geometry (R4) x lean body (R5/R6): unroll-1 + DMA staging
//   compiles at VGPR~40 under the 85-reg budget that (768,6) imposes ->
//   24 waves/CU without R4's spill.

typedef float f4 __attribute__((ext_vector_type(4)));
typedef const __attribute__((address_space(1))) f4 gf4;
typedef __attribute__((address_space(3))) f4 lf4;

#define N_      8
#define IC_     512
#define H_      96
#define W_      96
#define WC_     8
#define KS_     7
#define NG_     2
#define GSLOTS_ 32
#define XSLOTS_ 24
#define YC_     12
#define NTHR_   (XSLOTS_ * GSLOTS_)        // 768
#define WROW_F4_ (KS_ * KS_ * XSLOTS_)     // 1176 f4 per staged w row
#define WBUF_F4_ (WROW_F4_ + 40)           // pad: masked-DMA stray slots
#define NYT_    (H_ / YC_)                 // 8 ytiles

__global__ __launch_bounds__(NTHR_, 6)
void ska_kernel(const float* __restrict__ x, const float* __restrict__ w,
                float* __restrict__ out) {
    __shared__ f4 wlds[2][WBUF_F4_];       // 2 x 19456 B = 38912 B

    const int tid = threadIdx.x;

    // XCD-aware decode: consecutive blockIdx round-robins over 8 XCDs.
    // Keep all 8 ytiles of one (cw,n) on one XCD (L2-local halo rows).
    const int b     = blockIdx.x;          // 0..511
    const int xcd   = b & 7;
    const int q     = b >> 3;              // 0..63
    const int ytile = q & (NYT_ - 1);      // 0..7
    const int cwn   = xcd + 8 * (q >> 3);  // 0..63, cwn&7 == xcd
    const int cw    = cwn & 7;
    const int n     = cwn >> 3;
    const int y0    = ytile * YC_;

    const int x_slot = tid % XSLOTS_;      // 0..23
    const int g_slot = tid / XSLOTS_;      // 0..31
    const int xq     = x_slot * 4;         // output col base
    const int wavebase = tid & ~63;        // wave-uniform f4 base for DMA

    // w as f4: index (tap*H + y)*24 + x_slot within the (n,cw) plane
    const f4* wg = reinterpret_cast<const f4*>(w)
                 + (size_t)((n * WC_ + cw) * (KS_ * KS_)) * (H_ * W_ / 4);

    // per-gi channel plane offsets: g = gi*32 + g_slot, c = g*8 + cw
    int xoff[NG_], ooff[NG_];
#pragma unroll
    for (int gi = 0; gi < NG_; ++gi) {
        const int g     = gi * GSLOTS_ + g_slot;
        const int c     = g * WC_ + cw;
        const int plane = (n * IC_ + c) * (H_ * W_);
        xoff[gi] = plane + xq - 4;   // window starts at col xq-4
        ooff[gi] = plane + xq;
    }

    // stage one w row into wlds[nb] via direct global->LDS DMA.
    // f4 slot tid+768k == wave-uniform (wavebase+768k) + lane -> legal DMA.
    // tap = g_slot + 32k; tap<49 => k==0 always, k==1 iff g_slot<17.
    auto stage = [&](int nb, int yrow) {
#pragma unroll
        for (int k = 0; k < 2; ++k) {
            const int tap = g_slot + GSLOTS_ * k;
            if (k == 0 || g_slot < KS_ * KS_ - GSLOTS_) {  // tap < 49
                __builtin_amdgcn_global_load_lds(
                    (gf4*)(wg + (tap * H_ + yrow) * XSLOTS_ + x_slot),
                    (lf4*)(&wlds[nb][wavebase + NTHR_ * k]),
                    16, 0, 0);
            }
        }
    };

    stage(0, y0);
    __syncthreads();   // compiler drains vmcnt(0) before s_barrier

    for (int yt = 0; yt < YC_; ++yt) {
        const int y = y0 + yt;

        // issue next-row w DMA now; lands during compute, drained by the
        // end-of-row barrier.
        if (yt + 1 < YC_) stage((yt + 1) & 1, y + 1);

        const f4* wl = &wlds[yt & 1][0];

        float acc[NG_][4];
#pragma unroll
        for (int gi = 0; gi < NG_; ++gi)
#pragma unroll
            for (int k = 0; k < 4; ++k) acc[gi][k] = 0.f;

#pragma unroll 1   // CRITICAL: full unroll hoists 7 rows of A/B/C -> spills
        for (int i = 0; i < KS_; ++i) {
            const int ry = y + i - 3;
            if (ry >= 0 && ry < H_) {                      // block-uniform
                const int rbase = ry * W_;
                float win[NG_][12];
#pragma unroll
                for (int gi = 0; gi < NG_; ++gi) {
                    const float* rowp = x + xoff[gi] + rbase;
                    f4 A = (f4)0.f;
                    f4 C = (f4)0.f;
                    if (x_slot != 0)
                        A = *reinterpret_cast<const f4*>(rowp);
                    const f4 B = *reinterpret_cast<const f4*>(rowp + 4);
                    if (x_slot != XSLOTS_ - 1)
                        C = *reinterpret_cast<const f4*>(rowp + 8);
                    win[gi][0] = A.x;  win[gi][1] = A.y;
                    win[gi][2] = A.z;  win[gi][3] = A.w;
                    win[gi][4] = B.x;  win[gi][5] = B.y;
                    win[gi][6] = B.z;  win[gi][7] = B.w;
                    win[gi][8] = C.x;  win[gi][9] = C.y;
                    win[gi][10] = C.z; win[gi][11] = C.w;
                }
                const f4* wrow = wl + (i * KS_) * XSLOTS_ + x_slot;
#pragma unroll
                for (int j = 0; j < KS_; ++j) {
                    const f4 w4 = wrow[j * XSLOTS_];
                    const float wv[4] = {w4.x, w4.y, w4.z, w4.w};
#pragma unroll
                    for (int gi = 0; gi < NG_; ++gi)
#pragma unroll
                        for (int k = 0; k < 4; ++k)
                            acc[gi][k] = __builtin_fmaf(win[gi][1 + j + k],
                                                        wv[k], acc[gi][k]);
                }
            }
        }

        // store 2 channels x f4, written exactly once -> nontemporal
#pragma unroll
        for (int gi = 0; gi < NG_; ++gi) {
            f4 o;
            o.x = acc[gi][0]; o.y = acc[gi][1];
            o.z = acc[gi][2]; o.w = acc[gi][3];
            __builtin_nontemporal_store(
                o, reinterpret_cast<f4*>(out + ooff[gi] + y * W_));
        }

        // one barrier/row: drains the w DMA (vmcnt) and fences buffer reuse
        __syncthreads();
    }
}

extern "C" void kernel_launch(void* const* d_in, const int* in_sizes, int n_in,
                              void* d_out, int out_size, void* d_ws, size_t ws_size,
                              hipStream_t stream) {
    const float* x = reinterpret_cast<const float*>(d_in[0]);
    const float* w = reinterpret_cast<const float*>(d_in[1]);
    float* out     = reinterpret_cast<float*>(d_out);

    dim3 grid(NYT_ * WC_ * N_);      // 512 blocks, flat (XCD decode in-kernel)
    dim3 block(NTHR_);               // 768 threads = 12 waves
    hipLaunchKernelGGL(ska_kernel, grid, block, 0, stream, x, w, out);
}